// Round 13
// baseline (218.439 us; speedup 1.0000x reference)
//
#include <hip/hip_runtime.h>
#include <hip/hip_bf16.h>

#define NN 16384
#define DD 256

typedef unsigned short u16;
typedef unsigned int u32;
typedef unsigned char u8;
typedef long i64;
typedef __attribute__((ext_vector_type(2))) long i64x2;
typedef __attribute__((ext_vector_type(4))) float f32x4;
typedef __attribute__((ext_vector_type(16))) float f32x16;

// async global->LDS, 16B per lane; LDS dest = wave-uniform base + lane*16
static __device__ __forceinline__ void gload16(const u8* g, u8* l) {
    __builtin_amdgcn_global_load_lds(
        (const __attribute__((address_space(1))) void*)g,
        (__attribute__((address_space(3))) void*)l,
        16, 0, 0);
}

// ---------- kernel 1: fp8 e4m3 convert, pair-packed + XOR-swizzled ----------
// Both A8 and B8: per 128-row panel, row rl = 256 B = 16 chunks of 16 B.
// Logical chunk C = 2p + h holds k-bytes [2p*16 + h*8, +8) ++ [(2p+1)*16 + h*8, +8)
// (pair-packs k-steps 2p,2p+1 for one b128 per lane per pair; h = lane>>5 half).
// Stored at P = C ^ (rl & 7): 8 consecutive rows x b128 cover all 32 banks
// exactly once (R2/R12's verified-zero walk).
__global__ void prep_kernel(const float* __restrict__ img, const float* __restrict__ txt,
                            u8* __restrict__ A8, u8* __restrict__ B8,
                            float* __restrict__ zbuf /* s_row..s_col 32768 f */,
                            float* __restrict__ out) {
    int gid = blockIdx.x * 256 + threadIdx.x;          // 0 .. 1048575  (N*D/4)
    float4 va = ((const float4*)img)[gid];
    float4 vb = ((const float4*)txt)[gid];
    const float S = 1.44269504088896f;                  // log2(e) folded into A
    int pa = __builtin_amdgcn_cvt_pk_fp8_f32(va.x * S, va.y * S, 0, false);
    pa     = __builtin_amdgcn_cvt_pk_fp8_f32(va.z * S, va.w * S, pa, true);
    int pb = __builtin_amdgcn_cvt_pk_fp8_f32(vb.x, vb.y, 0, false);
    pb     = __builtin_amdgcn_cvt_pk_fp8_f32(vb.z, vb.w, pb, true);

    const int r  = gid >> 6;            // global row
    const int rl = r & 127;             // row within 128-panel
    const int pn = r >> 7;              // panel index
    const int ko = (gid & 63) << 2;     // k-byte offset 0..255, step 4
    const int s  = ko >> 4;             // k-step (K=16 granules), 0..15
    const int b  = ko & 15;
    const int h  = b >> 3;              // which 8-byte half of the k-step
    const int j  = b & 7;               // 0 or 4
    const int p  = s >> 1;              // k-step pair
    const int e  = s & 1;               // parity within pair
    const int C  = (p << 1) | h;
    const int P  = C ^ (rl & 7);
    const size_t off = ((size_t)pn << 15) + (rl << 8) + (P << 4) + (e << 3) + j;
    *(u32*)(A8 + off) = (u32)pa;
    *(u32*)(B8 + off) = (u32)pb;
    if (gid < 32768) zbuf[gid] = 0.0f;
    if (gid == 0) out[0] = 0.0f;
}

// ---------- kernel 2: fused fp8 GEMM (32x32x16) + exp2 + row/col sum + diag ----------
// R12 structure EXACTLY (A-once 32 KB, whole 32 KB B tile per jt, 2 barriers/tile,
// 64 KB LDS -> 2 blocks/CU, bi-fast grid, atomic s_row/s_col epilogue). Shape change:
// v_mfma_f32_32x32x16_fp8_fp8 -- 17% faster MFMA ceiling (m119), HALF the MFMA
// instructions and HALF the LDS reads (32 b128/tile/wave vs 64 b64).
// Wave = 64x64 as 2x2 blocks of 32x32; acc = f32x16 each.
// A/B frag: row|col = lane&31, k = (lane>>5)*8 + j.  C/D (m74/m101 verified):
// col = lane&31, row = (reg&3) + 8*(reg>>2) + 4*(lane>>5).
__global__ __launch_bounds__(256, 2) void gemm_lse_kernel(
        const u8* __restrict__ A8, const u8* __restrict__ B8,
        float* __restrict__ s_row, float* __restrict__ s_col,
        float* __restrict__ diag) {
    __shared__ u8 sA[32768];        // 128 rows x 256 B (pre-swizzled, pair-packed)
    __shared__ u8 sB[32768];

    const int t = threadIdx.x;
    const int lane = t & 63;
    const int w = t >> 6;
    const int wr = w >> 1, wc = w & 1;
    const int l31 = lane & 31;
    const int h = lane >> 5;
    const int bi = blockIdx.x & 127;            // FAST: resident blocks share B phase
    const int jg = blockIdx.x >> 7;
    const int row0 = bi << 7;

    // ---- stage A panel ONCE: linear 32 KB copy, 8 rounds x 256 lanes x 16 B
    #pragma unroll
    for (int R = 0; R < 8; ++R)
        gload16(A8 + ((size_t)bi << 15) + (R << 12) + (w << 10) + ((size_t)lane << 4),
                &sA[(R << 12) + (w << 10)]);

    const f32x16 fz16 = {0.f,0.f,0.f,0.f,0.f,0.f,0.f,0.f,0.f,0.f,0.f,0.f,0.f,0.f,0.f,0.f};
    f32x16 acc[2][2];
    f32x16 rp[2] = {fz16, fz16};              // row partials, whole block

    const int xr = l31 & 7;                   // row-derived XOR key (rb/wr don't affect &7)

    #pragma unroll 1
    for (int jt = 0; jt < 16; ++jt) {
        const int ct = (jg << 4) + jt;        // column tile index
        const int col0 = ct << 7;
        __syncthreads();   // all waves done with previous tile's sB
        #pragma unroll
        for (int R = 0; R < 8; ++R)
            gload16(B8 + ((size_t)ct << 15) + (R << 12) + (w << 10) + ((size_t)lane << 4),
                    &sB[(R << 12) + (w << 10)]);
        __syncthreads();   // drains vmcnt -> sB (and sA on jt=0) ready

        // ---- 64 MFMAs per wave, no barriers inside ----
        #pragma unroll
        for (int p = 0; p < 8; ++p) {
            const int P = (((p << 1) | h) ^ xr) << 4;
            i64x2 af[2], bf[2];
            #pragma unroll
            for (int rb = 0; rb < 2; ++rb) {
                const int rr = (wr << 6) + (rb << 5) + l31;
                af[rb] = *(const i64x2*)(&sA[(rr << 8) + P]);
                const int cr = (wc << 6) + (rb << 5) + l31;
                bf[rb] = *(const i64x2*)(&sB[(cr << 8) + P]);
            }
            if (p == 0) {
                #pragma unroll
                for (int rb = 0; rb < 2; ++rb)
                    #pragma unroll
                    for (int cb = 0; cb < 2; ++cb)
                        acc[rb][cb] = __builtin_amdgcn_mfma_f32_32x32x16_fp8_fp8(
                            af[rb].x, bf[cb].x, fz16, 0, 0, 0);
            } else {
                #pragma unroll
                for (int rb = 0; rb < 2; ++rb)
                    #pragma unroll
                    for (int cb = 0; cb < 2; ++cb)
                        acc[rb][cb] = __builtin_amdgcn_mfma_f32_32x32x16_fp8_fp8(
                            af[rb].x, bf[cb].x, acc[rb][cb], 0, 0, 0);
            }
            #pragma unroll
            for (int rb = 0; rb < 2; ++rb)
                #pragma unroll
                for (int cb = 0; cb < 2; ++cb)
                    acc[rb][cb] = __builtin_amdgcn_mfma_f32_32x32x16_fp8_fp8(
                        af[rb].y, bf[cb].y, acc[rb][cb], 0, 0, 0);
        }

        // ---- per-tile epilogue ----
        // diag (pre-exp, log2-scaled): row_in_32 = (g&3)+8*(g>>2)+4*h, col = l31
        if (bi == ct && wr == wc) {
            #pragma unroll
            for (int rb = 0; rb < 2; ++rb)
                #pragma unroll
                for (int g = 0; g < 16; ++g)
                    if (l31 == (((g & 3) + ((g >> 2) << 3)) + (h << 2)))
                        diag[row0 + (wr << 6) + (rb << 5) + l31] = acc[rb][rb][g];
        }
        // exp2(l' - 144) in place
        #pragma unroll
        for (int rb = 0; rb < 2; ++rb)
            #pragma unroll
            for (int cb = 0; cb < 2; ++cb)
                #pragma unroll
                for (int g = 0; g < 16; ++g)
                    acc[rb][cb][g] = __builtin_amdgcn_exp2f(acc[rb][cb][g] - 144.0f);

        // row partials: pure VALU, reduced once at block end
        #pragma unroll
        for (int rb = 0; rb < 2; ++rb)
            rp[rb] += acc[rb][0] + acc[rb][1];

        // col partials: sum 32 regs (both rb) + merge h-halves; col = wc*64+cb*32+l31
        #pragma unroll
        for (int cb = 0; cb < 2; ++cb) {
            float v = 0.0f;
            #pragma unroll
            for (int g = 0; g < 16; ++g)
                v += acc[0][cb][g] + acc[1][cb][g];
            v += __shfl_xor(v, 32, 64);
            if (h == 0)
                atomicAdd(&s_col[col0 + (wc << 6) + (cb << 5) + l31], v);
        }
    }

    // ---- block-end row reduction: rp[rb][g] is row (wr*64+rb*32+(g&3)+8*(g>>2)+4h),
    // distributed over the 32 col-lanes. Butterfly over l31, one writer per (g,h).
    #pragma unroll
    for (int rb = 0; rb < 2; ++rb)
        #pragma unroll
        for (int g = 0; g < 16; ++g) {
            float v = rp[rb][g];
            v += __shfl_xor(v, 1, 64);
            v += __shfl_xor(v, 2, 64);
            v += __shfl_xor(v, 4, 64);
            v += __shfl_xor(v, 8, 64);
            v += __shfl_xor(v, 16, 64);
            const int rw = ((g & 3) + ((g >> 2) << 3)) + (h << 2);
            if (l31 == rw)
                atomicAdd(&s_row[row0 + (wr << 6) + (rb << 5) + rw], v);
        }
}

// ---------- kernel 3: final reduce (64 blocks, 256 rows each) ----------
__global__ void final_kernel(const float* __restrict__ s_row, const float* __restrict__ s_col,
                             const float* __restrict__ diag, float* __restrict__ out) {
    __shared__ double red[256];
    int t = threadIdx.x;
    int i = blockIdx.x * 256 + t;
    double p = 0.5 * (double)(log2f(s_row[i]) + log2f(s_col[i])) + 144.0 - (double)diag[i];
    red[t] = p;
    __syncthreads();
    for (int s = 128; s > 0; s >>= 1) {
        if (t < s) red[t] += red[t + s];
        __syncthreads();
    }
    if (t == 0) atomicAdd(out, (float)(red[0] * 0.6931471805599453 / (double)NN));
}

// ---------- launch ----------
extern "C" void kernel_launch(void* const* d_in, const int* in_sizes, int n_in,
                              void* d_out, int out_size, void* d_ws, size_t ws_size,
                              hipStream_t stream) {
    const float* img = (const float*)d_in[0];
    const float* txt = (const float*)d_in[1];
    char* ws = (char*)d_ws;
    u8*    A8    = (u8*)ws;                                // 4 MB
    u8*    B8    = (u8*)(ws + 4194304);                    // 4 MB
    float* s_row = (float*)(ws + 8388608);                 // 64 KB
    float* s_col = (float*)(ws + 8388608 + 65536);         // 64 KB
    float* diag  = (float*)(ws + 8388608 + 131072);        // 64 KB
    float* out   = (float*)d_out;

    prep_kernel<<<4096, 256, 0, stream>>>(img, txt, A8, B8, s_row, out);
    gemm_lse_kernel<<<1024, 256, 0, stream>>>(A8, B8, s_row, s_col, diag);
    final_kernel<<<64, 256, 0, stream>>>(s_row, s_col, diag, out);
}

// Round 14
// 198.773 us; speedup vs baseline: 1.0989x; 1.0989x over previous
//
#include <hip/hip_runtime.h>
#include <hip/hip_bf16.h>

#define NN 16384
#define DD 256

typedef unsigned short u16;
typedef unsigned int u32;
typedef unsigned char u8;
typedef long i64;
typedef __attribute__((ext_vector_type(8))) int i32x8;
typedef __attribute__((ext_vector_type(4))) float f32x4;

// async global->LDS, 16B per lane; LDS dest = wave-uniform base + lane*16
static __device__ __forceinline__ void gload16(const u8* g, u8* l) {
    __builtin_amdgcn_global_load_lds(
        (const __attribute__((address_space(1))) void*)g,
        (__attribute__((address_space(3))) void*)l,
        16, 0, 0);
}

static __device__ __forceinline__ i32x8 pack4(i64 a, i64 b, i64 c, i64 d) {
    i32x8 v;
    v[0] = (int)a; v[1] = (int)(a >> 32);
    v[2] = (int)b; v[3] = (int)(b >> 32);
    v[4] = (int)c; v[5] = (int)(c >> 32);
    v[6] = (int)d; v[7] = (int)(d >> 32);
    return v;
}

// ---------- kernel 1: fp8 e4m3 convert, pre-swizzled (R12 layout VERBATIM) ----------
// A8: [bi][kc][rl][64 B rows], chunk cs at P=cs^((rl^(rl>>2))&3), half at (qq&1)^((rl>>3)&1).
// B8: [cb][rl][256 B rows], kc-block at kc^((rl>>1)&3), chunk cs at
//     P=cs^((((rl>>2)&1)<<1)|(rl&1)), half same key.  MEASURED: 0 bank conflicts (R12).
__global__ void prep_kernel(const float* __restrict__ img, const float* __restrict__ txt,
                            u8* __restrict__ A8, u8* __restrict__ B8,
                            float* __restrict__ zbuf /* s_row..s_col 32768 f */,
                            float* __restrict__ out) {
    int gid = blockIdx.x * 256 + threadIdx.x;          // 0 .. 1048575  (N*D/4)
    float4 va = ((const float4*)img)[gid];
    float4 vb = ((const float4*)txt)[gid];
    const float S = 1.44269504088896f;                  // log2(e) folded into A
    int pa = __builtin_amdgcn_cvt_pk_fp8_f32(va.x * S, va.y * S, 0, false);
    pa     = __builtin_amdgcn_cvt_pk_fp8_f32(va.z * S, va.w * S, pa, true);
    int pb = __builtin_amdgcn_cvt_pk_fp8_f32(vb.x, vb.y, 0, false);
    pb     = __builtin_amdgcn_cvt_pk_fp8_f32(vb.z, vb.w, pb, true);

    const int r  = gid >> 6;            // global row
    const int rl = r & 127;             // row within 128-panel
    const int pn = r >> 7;              // panel (bi / cb)
    const int ko = (gid & 63) << 2;     // k-byte offset 0..255, step 4
    const int J  = ko >> 3;             // 8-byte slot 0..31
    const int u  = ko & 7;              // 0 or 4
    const int kc = J >> 3;
    const int s  = (J >> 2) & 1;
    const int qq = J & 3;
    const int cs = (s << 1) | (qq >> 1);
    const int hh = (qq & 1) ^ ((rl >> 3) & 1);
    {
        const int P = cs ^ ((rl ^ (rl >> 2)) & 3);
        *(u32*)(A8 + ((size_t)pn << 15) + (kc << 13) + (rl << 6)
                   + (P << 4) + (hh << 3) + u) = (u32)pa;
    }
    {
        const int kp = kc ^ ((rl >> 1) & 3);
        const int P  = cs ^ (((( rl >> 2) & 1) << 1) | (rl & 1));
        *(u32*)(B8 + ((size_t)pn << 15) + (rl << 8) + (kp << 6)
                   + (P << 4) + (hh << 3) + u) = (u32)pb;
    }
    if (gid < 32768) zbuf[gid] = 0.0f;
    if (gid == 0) out[0] = 0.0f;
}

// ---------- kernel 2: fused MX-fp8 GEMM (16x16x128 scaled) + exp2 + sums + diag ----------
// R12's memory system BYTE-IDENTICAL (measured: 0 conflicts, 18.5/17.5 MB HBM,
// gemm 137 us): A-once 32 KB, whole 32 KB B tile per jt, 2 barriers/tile,
// 64 KB LDS -> 2 blocks/CU, bi-fast grid, atomic s_row/s_col epilogue, and the
// SAME 32+32 b64 LDS reads per tile-wave at the SAME addresses.
// Only change: 128 16x16x32 MFMAs/tile/wave -> 32 mfma_scale 16x16x128 (unit
// e8m0 scales = exact x1.0), ~2x MFMA rate (m21/m148): per-CU MFMA-busy
// 132k -> ~70k cyc. Within-lane k-packing cancels between A and B (dot-product
// invariance), so feeding R12's four b64 slices per K=128 half in identical
// order for A and B is exactly correct. C/D layout is shape-determined
// (m121-128, verified incl. f8f6f4-scaled) -> epilogue unchanged.
__global__ __launch_bounds__(256, 2) void gemm_lse_kernel(
        const u8* __restrict__ A8, const u8* __restrict__ B8,
        float* __restrict__ s_row, float* __restrict__ s_col,
        float* __restrict__ diag) {
    __shared__ u8 sA[32768];        // [kc][128 rows][64 B]  (pre-swizzled)
    __shared__ u8 sB[32768];        // [128 rows][256 B]     (pre-swizzled)

    const int t = threadIdx.x;
    const int lane = t & 63;
    const int w = t >> 6;
    const int wr = w >> 1, wc = w & 1;
    const int q = lane >> 4, m = lane & 15;
    const int bi = blockIdx.x & 127;            // FAST: resident blocks share B phase
    const int jg = blockIdx.x >> 7;
    const int row0 = bi << 7;

    // ---- stage A panel ONCE: linear 32 KB copy
    #pragma unroll
    for (int R = 0; R < 8; ++R)
        gload16(A8 + ((size_t)bi << 15) + (R << 12) + (w << 10) + ((size_t)lane << 4),
                &sA[(R << 12) + (w << 10)]);

    const f32x4 fzero = {0.f, 0.f, 0.f, 0.f};
    f32x4 acc[4][4];
    f32x4 rp[4] = {fzero, fzero, fzero, fzero};   // row partials, whole block

    #pragma unroll 1
    for (int jt = 0; jt < 16; ++jt) {
        const int ct = (jg << 4) + jt;            // column tile index
        const int col0 = ct << 7;
        __syncthreads();   // all waves done computing previous tile from sB
        #pragma unroll
        for (int R = 0; R < 8; ++R)
            gload16(B8 + ((size_t)ct << 15) + (R << 12) + (w << 10) + ((size_t)lane << 4),
                    &sB[(R << 12) + (w << 10)]);
        __syncthreads();   // drains vmcnt -> sB (and sA on jt=0) ready

        // ---- 32 scaled MFMAs per wave, no barriers inside ----
        #pragma unroll
        for (int ki = 0; ki < 2; ++ki) {
            i32x8 av[4], bv[4];
            #pragma unroll
            for (int rb = 0; rb < 4; ++rb) {
                const int rr = (wr << 6) + (rb << 4) + m;
                const int ra = (rr ^ (rr >> 2)) & 3;
                const int hA = ((q & 1) ^ ((rr >> 3) & 1)) << 3;
                const int cr = (wc << 6) + (rb << 4) + m;
                const int rbx = (((cr >> 2) & 1) << 1) | (cr & 1);
                const int hB = ((q & 1) ^ ((cr >> 3) & 1)) << 3;
                i64 aS[4], bS[4];
                #pragma unroll
                for (int d = 0; d < 2; ++d) {
                    const int kc = (ki << 1) + d;
                    const int kp = kc ^ ((cr >> 1) & 3);
                    #pragma unroll
                    for (int e = 0; e < 2; ++e) {
                        const int cs = (e << 1) | (q >> 1);
                        const int PA = cs ^ ra;
                        aS[(d << 1) | e] = *(const i64*)(&sA[(kc << 13) + (rr << 6) + (PA << 4) + hA]);
                        const int PB = cs ^ rbx;
                        bS[(d << 1) | e] = *(const i64*)(&sB[(cr << 8) + (kp << 6) + (PB << 4) + hB]);
                    }
                }
                av[rb] = pack4(aS[0], aS[1], aS[2], aS[3]);
                bv[rb] = pack4(bS[0], bS[1], bS[2], bS[3]);
            }
            if (ki == 0) {
                #pragma unroll
                for (int rb = 0; rb < 4; ++rb)
                    #pragma unroll
                    for (int cb = 0; cb < 4; ++cb)
                        acc[rb][cb] = __builtin_amdgcn_mfma_scale_f32_16x16x128_f8f6f4(
                            av[rb], bv[cb], fzero, 0, 0,
                            0, 0x7F7F7F7F, 0, 0x7F7F7F7F);
            } else {
                #pragma unroll
                for (int rb = 0; rb < 4; ++rb)
                    #pragma unroll
                    for (int cb = 0; cb < 4; ++cb)
                        acc[rb][cb] = __builtin_amdgcn_mfma_scale_f32_16x16x128_f8f6f4(
                            av[rb], bv[cb], acc[rb][cb], 0, 0,
                            0, 0x7F7F7F7F, 0, 0x7F7F7F7F);
            }
        }

        // ---- per-tile epilogue (R12's exact form; C/D: col=m, row=q*4+r) ----
        if (bi == ct && wr == wc) {
            #pragma unroll
            for (int rb = 0; rb < 4; ++rb)
                #pragma unroll
                for (int r = 0; r < 4; ++r)
                    if (m == ((q << 2) | r))
                        diag[row0 + (wr << 6) + (rb << 4) + m] = acc[rb][rb][r];
        }
        #pragma unroll
        for (int rb = 0; rb < 4; ++rb)
            #pragma unroll
            for (int cb = 0; cb < 4; ++cb)
                #pragma unroll
                for (int r = 0; r < 4; ++r)
                    acc[rb][cb][r] = __builtin_amdgcn_exp2f(acc[rb][cb][r] - 144.0f);

        #pragma unroll
        for (int rb = 0; rb < 4; ++rb)
            rp[rb] += (acc[rb][0] + acc[rb][1]) + (acc[rb][2] + acc[rb][3]);

        float cpart = 0.0f;
        #pragma unroll
        for (int cb = 0; cb < 4; ++cb) {
            float v = 0.0f;
            #pragma unroll
            for (int rb = 0; rb < 4; ++rb)
                v += (acc[rb][cb][0] + acc[rb][cb][1]) + (acc[rb][cb][2] + acc[rb][cb][3]);
            v += __shfl_xor(v, 16, 64);
            v += __shfl_xor(v, 32, 64);
            if (q == cb) cpart = v;
        }
        atomicAdd(&s_col[col0 + (wc << 6) + (q << 4) + m], cpart);
    }

    // ---- block-end row reduction ----
    float rout = 0.0f;
    #pragma unroll
    for (int rb = 0; rb < 4; ++rb)
        #pragma unroll
        for (int r = 0; r < 4; ++r) {
            float v = rp[rb][r];
            v += __shfl_xor(v, 1, 16);
            v += __shfl_xor(v, 2, 16);
            v += __shfl_xor(v, 4, 16);
            v += __shfl_xor(v, 8, 16);
            if (m == ((rb << 2) | r)) rout = v;
        }
    atomicAdd(&s_row[row0 + (wr << 6) + ((m >> 2) << 4) + (q << 2) + (m & 3)], rout);
}

// ---------- kernel 3: final reduce (64 blocks, 256 rows each) ----------
__global__ void final_kernel(const float* __restrict__ s_row, const float* __restrict__ s_col,
                             const float* __restrict__ diag, float* __restrict__ out) {
    __shared__ double red[256];
    int t = threadIdx.x;
    int i = blockIdx.x * 256 + t;
    double p = 0.5 * (double)(log2f(s_row[i]) + log2f(s_col[i])) + 144.0 - (double)diag[i];
    red[t] = p;
    __syncthreads();
    for (int s = 128; s > 0; s >>= 1) {
        if (t < s) red[t] += red[t + s];
        __syncthreads();
    }
    if (t == 0) atomicAdd(out, (float)(red[0] * 0.6931471805599453 / (double)NN));
}

// ---------- launch ----------
extern "C" void kernel_launch(void* const* d_in, const int* in_sizes, int n_in,
                              void* d_out, int out_size, void* d_ws, size_t ws_size,
                              hipStream_t stream) {
    const float* img = (const float*)d_in[0];
    const float* txt = (const float*)d_in[1];
    char* ws = (char*)d_ws;
    u8*    A8    = (u8*)ws;                                // 4 MB
    u8*    B8    = (u8*)(ws + 4194304);                    // 4 MB
    float* s_row = (float*)(ws + 8388608);                 // 64 KB
    float* s_col = (float*)(ws + 8388608 + 65536);         // 64 KB
    float* diag  = (float*)(ws + 8388608 + 131072);        // 64 KB
    float* out   = (float*)d_out;

    prep_kernel<<<4096, 256, 0, stream>>>(img, txt, A8, B8, s_row, out);
    gemm_lse_kernel<<<1024, 256, 0, stream>>>(A8, B8, s_row, s_col, diag);
    final_kernel<<<64, 256, 0, stream>>>(s_row, s_col, diag, out);
}